// Round 1
// baseline (233.325 us; speedup 1.0000x reference)
//
#include <hip/hip_runtime.h>
#include <math.h>

#define B 4
#define CIN 8
#define COUT 16
#define OR_ 8
#define H_ 128
#define W_ 128
#define HW 16384
#define PLANE HW
#define CH_STR (OR_*HW)        // 131072
#define BATCH_STR (CIN*CH_STR) // 1048576
#define NELEM (B*BATCH_STR)    // 4194304
#define NPOS (B*OR_*HW)        // 524288
#define NB_RED 512

struct Tables {
  float kdil[CIN][27];
  float kero[CIN][27];
  int   conv_i[CIN];
  float conv_f[CIN];
  float conv_dy[CIN][OR_];
  float conv_dx[CIN][OR_];
  float mdy[OR_][9];
  float mdx[OR_][9];
};

__global__ void precompute_kernel(const float* __restrict__ g0,
                                  const float* __restrict__ mdil,
                                  const float* __restrict__ mero,
                                  Tables* __restrict__ T) {
  const int t = threadIdx.x;
  const double TWO_PI = 6.283185307179586476925286766559;
  const double P  = 2.0*0.65/(2.0*0.65 - 1.0);        // 4.3333...
  const double NU = (2.0*0.65 - 1.0)*pow(2.0*0.65, -P);
  if (t < 432) {
    int which = t / 216;           // 0 = dilate, 1 = erode
    int r = t % 216;
    int c = r / 27;
    int j = r % 27;                // j = (qt+1)*9 + (qy+1)*3 + (qx+1)
    int qt = j/9 - 1;
    int qy = (j/3)%3 - 1;
    int qx = j%3 - 1;
    double dth = qt * (TWO_PI/OR_);
    double c1, c2, c3;
    if (qt == 0) { c1 = qx; c2 = qy; c3 = 0.0; }
    else {
      double h = 0.5*dth;
      double cot = cos(h)/sin(h);
      c1 = h*(qx*cot + qy);
      c2 = h*(-qx + qy*cot);
      c3 = dth;
    }
    const float* m = which ? mero : mdil;
    double a0 = (double)m[c*3+0]*c1;
    double a1 = (double)m[c*3+1]*c2;
    double a2 = (double)m[c*3+2]*c3;
    double s = a0*a0 + a1*a1 + a2*a2;
    float k = (float)(NU * pow(s, P*0.5));
    if (which) T->kero[c][j] = k; else T->kdil[c][j] = k;
  } else if (t >= 512 && t < 512 + CIN*OR_) {
    int r = t - 512;
    int c = r / OR_;
    int o = r % OR_;
    float x0 = g0[c*3+0], y0 = g0[c*3+1], th0 = g0[c*3+2];
    float a = (float)(o*(TWO_PI/OR_)) - th0;
    float ca = cosf(a), sa = sinf(a);
    T->conv_dx[c][o] = -(ca*x0 - sa*y0);
    T->conv_dy[c][o] = -(sa*x0 + ca*y0);
    if (o == 0) {
      float tt = th0 * (float)(OR_/TWO_PI);
      float fi = floorf(tt);
      T->conv_i[c] = (int)fi;
      T->conv_f[c] = tt - fi;
    }
  } else if (t >= 640 && t < 640 + OR_*9) {
    int r = t - 640;
    int o = r / 9;
    int j = r % 9;                 // j = (qy+1)*3 + (qx+1)
    int qy = j/3 - 1, qx = j%3 - 1;
    float th = (float)(o*(TWO_PI/OR_));
    float ct = cosf(th), st = sinf(th);
    T->mdx[o][j] = ct*qx - st*qy;
    T->mdy[o][j] = st*qx + ct*qy;
  }
}

__global__ void conv_kernel(const float* __restrict__ x, float* __restrict__ out,
                            const Tables* __restrict__ T) {
  int idx = blockIdx.x*256 + threadIdx.x;
  int w = idx & 127;
  int h = (idx >> 7) & 127;
  int o = (idx >> 14) & 7;
  int c = (idx >> 17) & 7;
  int b = idx >> 20;
  int i = T->conv_i[c];
  float f = T->conv_f[c];
  int o1 = (o - i) & 7;
  int o2 = (o - i - 1) & 7;
  const float* p1 = x + b*BATCH_STR + c*CH_STR + o1*PLANE;
  const float* p2 = x + b*BATCH_STR + c*CH_STR + o2*PLANE;
  float dy = T->conv_dy[c][o], dx = T->conv_dx[c][o];
  float fy0 = floorf(dy); float fy = dy - fy0;
  float fx0 = floorf(dx); float fx = dx - fx0;
  int iy = h + (int)fy0;
  int ix = w + (int)fx0;
  int r0 = min(max(iy, 0), 127), r1 = min(max(iy+1, 0), 127);
  int c0 = min(max(ix, 0), 127), c1 = min(max(ix+1, 0), 127);
  float w00 = (1.f-fy)*(1.f-fx), w01 = (1.f-fy)*fx, w10 = fy*(1.f-fx), w11 = fy*fx;
  float v1 = w00*p1[r0*W_+c0] + w01*p1[r0*W_+c1] + w10*p1[r1*W_+c0] + w11*p1[r1*W_+c1];
  float v2 = w00*p2[r0*W_+c0] + w01*p2[r0*W_+c1] + w10*p2[r1*W_+c0] + w11*p2[r1*W_+c1];
  out[idx] = (1.0f - f)*v1 + f*v2;
}

template<int DIL>
__global__ void morph_kernel(const float* __restrict__ in, float* __restrict__ out,
                             const Tables* __restrict__ T) {
  int idx = blockIdx.x*256 + threadIdx.x;
  int w = idx & 127;
  int h = (idx >> 7) & 127;
  int o = (idx >> 14) & 7;
  int c = (idx >> 17) & 7;
  int b = idx >> 20;
  const float* base = in + b*BATCH_STR + c*CH_STR;
  const float* kt = DIL ? T->kdil[c] : T->kero[c];
  const float* p0 = base + ((o-1)&7)*PLANE;  // qt = -1 -> src o-1? NO: src = (o+qt)&7
  const float* p1 = base + o*PLANE;
  const float* p2 = base + ((o+1)&7)*PLANE;
  // qt index 0,1,2 <-> qt=-1,0,+1 : source orientation (o+qt)&7
  const float* planes[3] = { p0, p1, p2 };
  float acc = DIL ? -INFINITY : INFINITY;
  #pragma unroll
  for (int j = 0; j < 9; ++j) {
    float dy = T->mdy[o][j], dx = T->mdx[o][j];
    float fy0 = floorf(dy), fx0 = floorf(dx);
    float fy = dy - fy0, fx = dx - fx0;
    int iy = h + (int)fy0, ix = w + (int)fx0;
    int r0 = min(max(iy, 0), 127), r1 = min(max(iy+1, 0), 127);
    int c0 = min(max(ix, 0), 127), c1 = min(max(ix+1, 0), 127);
    int i00 = r0*W_+c0, i01 = r0*W_+c1, i10 = r1*W_+c0, i11 = r1*W_+c1;
    float w00 = (1.f-fy)*(1.f-fx), w01 = (1.f-fy)*fx, w10 = fy*(1.f-fx), w11 = fy*fx;
    #pragma unroll
    for (int q = 0; q < 3; ++q) {
      const float* p = planes[q];
      float val = w00*p[i00] + w01*p[i01] + w10*p[i10] + w11*p[i11];
      float k = kt[q*9 + j];
      float cand = DIL ? (val - k) : (val + k);
      acc = DIL ? fmaxf(acc, cand) : fminf(acc, cand);
    }
  }
  out[idx] = acc;
}

// Wait — planes[0] must be source (o-1)&7 for qt=-1: (o + (-1)) & 7 = (o-1)&7.  OK.

__global__ void gram_kernel(const float* __restrict__ u, double* __restrict__ part) {
  double S[8];
  double G[36];
  #pragma unroll
  for (int i = 0; i < 8; i++) S[i] = 0.0;
  #pragma unroll
  for (int i = 0; i < 36; i++) G[i] = 0.0;
  for (int p = blockIdx.x*256 + threadIdx.x; p < NPOS; p += NB_RED*256) {
    int hw = p & 16383;
    int o  = (p >> 14) & 7;
    int b  = p >> 17;
    const float* base = u + b*BATCH_STR + o*PLANE + hw;
    float v[8];
    #pragma unroll
    for (int c = 0; c < 8; c++) v[c] = base[c*CH_STR];
    int t = 0;
    #pragma unroll
    for (int c = 0; c < 8; c++) {
      S[c] += (double)v[c];
      #pragma unroll
      for (int c2 = c; c2 < 8; c2++) { G[t] += (double)v[c]*(double)v[c2]; t++; }
    }
  }
  __shared__ double lds[4][44];
  int lane = threadIdx.x & 63;
  int wave = threadIdx.x >> 6;
  for (int t = 0; t < 44; t++) {
    double v = (t < 8) ? S[t] : G[t-8];
    for (int off = 32; off; off >>= 1) v += __shfl_down(v, off);
    if (lane == 0) lds[wave][t] = v;
  }
  __syncthreads();
  if (threadIdx.x < 44) {
    part[blockIdx.x*44 + threadIdx.x] =
      lds[0][threadIdx.x] + lds[1][threadIdx.x] + lds[2][threadIdx.x] + lds[3][threadIdx.x];
  }
}

__global__ void stats_kernel(const double* __restrict__ part, const float* __restrict__ weight,
                             const float* __restrict__ gamma, const float* __restrict__ beta,
                             float* __restrict__ ss) {
  __shared__ double tot[44];
  int t = threadIdx.x;
  if (t < 44) {
    double s = 0.0;
    for (int bidx = 0; bidx < NB_RED; bidx++) s += part[bidx*44 + t];
    tot[t] = s;
  }
  __syncthreads();
  if (t < 16) {
    double m = 0.0;
    for (int c = 0; c < 8; c++) m += (double)weight[c*COUT + t] * tot[c];
    double e2 = 0.0;
    int idx = 8;
    for (int c = 0; c < 8; c++)
      for (int c2 = c; c2 < 8; c2++) {
        double wp = (double)weight[c*COUT + t] * (double)weight[c2*COUT + t];
        e2 += (c2 == c ? 1.0 : 2.0) * wp * tot[idx];
        idx++;
      }
    double N = (double)NPOS;
    m /= N; e2 /= N;
    double var = e2 - m*m;
    double inv = rsqrt(var + 1e-5);
    float sc = (float)(inv * (double)gamma[t]);
    ss[t]      = sc;
    ss[16 + t] = beta[t] - (float)m * sc;
  }
}

__global__ void final_kernel(const float* __restrict__ u, const float* __restrict__ weight,
                             const float* __restrict__ ss, float* __restrict__ out) {
  __shared__ float Wsh[8][16];
  __shared__ float scale[16], shift[16];
  int t = threadIdx.x;
  if (t < 128) Wsh[t >> 4][t & 15] = weight[t];
  if (t < 16) { scale[t] = ss[t]; shift[t] = ss[16 + t]; }
  __syncthreads();
  int p = blockIdx.x*256 + threadIdx.x;
  int hw = p & 16383;
  int o  = (p >> 14) & 7;
  int b  = p >> 17;
  const float* base = u + b*BATCH_STR + o*PLANE + hw;
  float v[8];
  #pragma unroll
  for (int c = 0; c < 8; c++) v[c] = base[c*CH_STR];
  float* ob = out + b*(COUT*CH_STR) + o*PLANE + hw;
  #pragma unroll
  for (int d = 0; d < 16; d++) {
    float y = 0.f;
    #pragma unroll
    for (int c = 0; c < 8; c++) y = fmaf(v[c], Wsh[c][d], y);
    ob[d*CH_STR] = fmaf(y, scale[d], shift[d]);
  }
}

extern "C" void kernel_launch(void* const* d_in, const int* in_sizes, int n_in,
                              void* d_out, int out_size, void* d_ws, size_t ws_size,
                              hipStream_t stream) {
  const float* x      = (const float*)d_in[0];
  const float* g0     = (const float*)d_in[1];
  const float* mdil   = (const float*)d_in[2];
  const float* mero   = (const float*)d_in[3];
  const float* weight = (const float*)d_in[4];
  const float* gamma  = (const float*)d_in[5];
  const float* beta   = (const float*)d_in[6];
  float* out = (float*)d_out;

  char* ws = (char*)d_ws;
  Tables* T   = (Tables*)ws;                    // ~3 KB
  float*  ss  = (float*)(ws + 8*1024);          // 32 floats
  double* part = (double*)(ws + 16*1024);       // 512*44*8 = 180 KB
  float*  u3  = (float*)(ws + 1024*1024);       // 16 MiB

  float* u1 = out;          // first half of d_out as scratch
  float* u2 = out + NELEM;  // second half of d_out as scratch

  precompute_kernel<<<1, 1024, 0, stream>>>(g0, mdil, mero, T);
  conv_kernel<<<NELEM/256, 256, 0, stream>>>(x, u1, T);
  morph_kernel<1><<<NELEM/256, 256, 0, stream>>>(u1, u2, T);
  morph_kernel<0><<<NELEM/256, 256, 0, stream>>>(u2, u3, T);
  gram_kernel<<<NB_RED, 256, 0, stream>>>(u3, part);
  stats_kernel<<<1, 64, 0, stream>>>(part, weight, gamma, beta, ss);
  final_kernel<<<NPOS/256, 256, 0, stream>>>(u3, weight, ss, out);
}

// Round 2
// 150.562 us; speedup vs baseline: 1.5497x; 1.5497x over previous
//
#include <hip/hip_runtime.h>
#include <math.h>
#include <utility>

#define B 4
#define CIN 8
#define COUT 16
#define OR_ 8
#define H_ 128
#define W_ 128
#define HW 16384
#define PLANE HW
#define CH_STR (OR_*HW)        // 131072
#define BATCH_STR (CIN*CH_STR) // 1048576
#define NELEM (B*BATCH_STR)    // 4194304
#define NPOS (B*OR_*HW)        // 524288
#define NB_RED 512

struct Tables {
  float kdil[CIN][27];
  float kero[CIN][27];
  int   conv_i[CIN];
  float conv_f[CIN];
  float conv_dy[CIN][OR_];
  float conv_dx[CIN][OR_];
};

// ---------------- compile-time tap geometry for morph ----------------
// theta_o = o * pi/4  ->  cos/sin in {0, +-1, +-r}, r = sqrt(2)/2
__host__ __device__ constexpr double m_cos(int o) {
  const double r = 0.70710678118654752440;
  const double t[8] = {1.0, r, 0.0, -r, -1.0, -r, 0.0, r};
  return t[o];
}
__host__ __device__ constexpr double m_sin(int o) {
  const double r = 0.70710678118654752440;
  const double t[8] = {0.0, r, 1.0, r, 0.0, -r, -1.0, -r};
  return t[o];
}
// j = (qy+1)*3 + (qx+1)
__host__ __device__ constexpr double tap_dx(int o, int j) {
  return m_cos(o)*(j % 3 - 1) - m_sin(o)*(j / 3 - 1);
}
__host__ __device__ constexpr double tap_dy(int o, int j) {
  return m_sin(o)*(j % 3 - 1) + m_cos(o)*(j / 3 - 1);
}
__host__ __device__ constexpr int ifloor(double v) {
  int i = (int)v;
  return ((double)i > v) ? i - 1 : i;
}
__host__ __device__ constexpr int tap_ix(int o, int j) { return ifloor(tap_dx(o, j)); } // in [-2,1]
__host__ __device__ constexpr int tap_iy(int o, int j) { return ifloor(tap_dy(o, j)); }
__host__ __device__ constexpr float tap_fx(int o, int j) { return (float)(tap_dx(o, j) - tap_ix(o, j)); }
__host__ __device__ constexpr float tap_fy(int o, int j) { return (float)(tap_dy(o, j) - tap_iy(o, j)); }
// corner (dyb,dxb) in {0,1}^2; cell index in 5x5 neighborhood (rows -2..2, cols -2..2)
__host__ __device__ constexpr int corner_cell(int o, int j, int dyb, int dxb) {
  return (tap_iy(o, j) + 2 + dyb) * 5 + (tap_ix(o, j) + 2 + dxb);
}
__host__ __device__ constexpr float corner_w(int o, int j, int dyb, int dxb) {
  float fy = tap_fy(o, j), fx = tap_fx(o, j);
  return (dyb ? fy : 1.0f - fy) * (dxb ? fx : 1.0f - fx);
}
__host__ __device__ constexpr bool cell_used(int o, int cell) {
  for (int j = 0; j < 9; ++j)
    for (int dyb = 0; dyb < 2; ++dyb)
      for (int dxb = 0; dxb < 2; ++dxb)
        if (corner_w(o, j, dyb, dxb) != 0.0f && corner_cell(o, j, dyb, dxb) == cell)
          return true;
  return false;
}

template<int N> struct Rep {
  template<class F> __device__ __forceinline__ static void run(F&& f) {
    Rep<N-1>::run(f);
    f(std::integral_constant<int, N-1>{});
  }
};
template<> struct Rep<0> {
  template<class F> __device__ __forceinline__ static void run(F&&) {}
};

// ---------------- kernels ----------------

__global__ void precompute_kernel(const float* __restrict__ g0,
                                  const float* __restrict__ mdil,
                                  const float* __restrict__ mero,
                                  Tables* __restrict__ T) {
  const int t = threadIdx.x;
  const double TWO_PI = 6.283185307179586476925286766559;
  const double P  = 2.0*0.65/(2.0*0.65 - 1.0);
  const double NU = (2.0*0.65 - 1.0)*pow(2.0*0.65, -P);
  if (t < 432) {
    int which = t / 216;           // 0 = dilate, 1 = erode
    int r = t % 216;
    int c = r / 27;
    int j = r % 27;                // j = (qt+1)*9 + (qy+1)*3 + (qx+1)
    int qt = j/9 - 1;
    int qy = (j/3)%3 - 1;
    int qx = j%3 - 1;
    double dth = qt * (TWO_PI/OR_);
    double c1, c2, c3;
    if (qt == 0) { c1 = qx; c2 = qy; c3 = 0.0; }
    else {
      double h = 0.5*dth;
      double cot = cos(h)/sin(h);
      c1 = h*(qx*cot + qy);
      c2 = h*(-qx + qy*cot);
      c3 = dth;
    }
    const float* m = which ? mero : mdil;
    double a0 = (double)m[c*3+0]*c1;
    double a1 = (double)m[c*3+1]*c2;
    double a2 = (double)m[c*3+2]*c3;
    double s = a0*a0 + a1*a1 + a2*a2;
    float k = (float)(NU * pow(s, P*0.5));
    if (which) T->kero[c][j] = k; else T->kdil[c][j] = k;
  } else if (t >= 512 && t < 512 + CIN*OR_) {
    int r = t - 512;
    int c = r / OR_;
    int o = r % OR_;
    float x0 = g0[c*3+0], y0 = g0[c*3+1], th0 = g0[c*3+2];
    float a = (float)(o*(TWO_PI/OR_)) - th0;
    float ca = cosf(a), sa = sinf(a);
    T->conv_dx[c][o] = -(ca*x0 - sa*y0);
    T->conv_dy[c][o] = -(sa*x0 + ca*y0);
    if (o == 0) {
      float tt = th0 * (float)(OR_/TWO_PI);
      float fi = floorf(tt);
      T->conv_i[c] = (int)fi;
      T->conv_f[c] = tt - fi;
    }
  }
}

__global__ void conv_kernel(const float* __restrict__ x, float* __restrict__ out,
                            const Tables* __restrict__ T) {
  int idx = blockIdx.x*256 + threadIdx.x;
  int w = idx & 127;
  int h = (idx >> 7) & 127;
  int o = (idx >> 14) & 7;
  int c = (idx >> 17) & 7;
  int b = idx >> 20;
  int i = T->conv_i[c];
  float f = T->conv_f[c];
  int o1 = (o - i) & 7;
  int o2 = (o - i - 1) & 7;
  const float* p1 = x + b*BATCH_STR + c*CH_STR + o1*PLANE;
  const float* p2 = x + b*BATCH_STR + c*CH_STR + o2*PLANE;
  float dy = T->conv_dy[c][o], dx = T->conv_dx[c][o];
  float fy0 = floorf(dy); float fy = dy - fy0;
  float fx0 = floorf(dx); float fx = dx - fx0;
  int iy = h + (int)fy0;
  int ix = w + (int)fx0;
  int r0 = min(max(iy, 0), 127), r1 = min(max(iy+1, 0), 127);
  int c0 = min(max(ix, 0), 127), c1 = min(max(ix+1, 0), 127);
  float w00 = (1.f-fy)*(1.f-fx), w01 = (1.f-fy)*fx, w10 = fy*(1.f-fx), w11 = fy*fx;
  float v1 = w00*p1[r0*W_+c0] + w01*p1[r0*W_+c1] + w10*p1[r1*W_+c0] + w11*p1[r1*W_+c1];
  float v2 = w00*p2[r0*W_+c0] + w01*p2[r0*W_+c1] + w10*p2[r1*W_+c0] + w11*p2[r1*W_+c1];
  out[idx] = (1.0f - f)*v1 + f*v2;
}

// Morph body with all tap geometry compile-time. Loads only the cells of the
// 5x5 neighborhood actually touched by some nonzero-weight corner (9 for even
// o, 13 for odd o), statically indexed so everything stays in registers.
template<int O, int DIL>
__device__ __forceinline__ float morph_body(const float* __restrict__ base,
                                            const float* __restrict__ kt,
                                            int h, int w) {
  int rr[5], cc[5];
  #pragma unroll
  for (int i = 0; i < 5; ++i) {
    rr[i] = min(max(h - 2 + i, 0), 127) << 9;  // byte row offset (128 floats * 4B)
    cc[i] = min(max(w - 2 + i, 0), 127) << 2;  // byte col offset
  }
  int off[25];
  Rep<25>::run([&](auto ic) {
    constexpr int cell = decltype(ic)::value;
    if constexpr (cell_used(O, cell)) off[cell] = rr[cell / 5] + cc[cell % 5];
  });

  float acc = DIL ? -INFINITY : INFINITY;
  #pragma unroll
  for (int qti = 0; qti < 3; ++qti) {
    const float* p = base + ((O + qti + 7) & 7) * PLANE;   // source orientation (O+qt)&7
    float cv[25];
    Rep<25>::run([&](auto ic) {
      constexpr int cell = decltype(ic)::value;
      if constexpr (cell_used(O, cell))
        cv[cell] = *(const float*)((const char*)p + off[cell]);
    });
    Rep<9>::run([&](auto jc) {
      constexpr int j = decltype(jc)::value;
      float k = kt[qti*9 + j];
      float v = DIL ? -k : k;
      constexpr float W00 = corner_w(O, j, 0, 0);
      constexpr float W01 = corner_w(O, j, 0, 1);
      constexpr float W10 = corner_w(O, j, 1, 0);
      constexpr float W11 = corner_w(O, j, 1, 1);
      if constexpr (W00 != 0.0f) v = fmaf(W00, cv[corner_cell(O, j, 0, 0)], v);
      if constexpr (W01 != 0.0f) v = fmaf(W01, cv[corner_cell(O, j, 0, 1)], v);
      if constexpr (W10 != 0.0f) v = fmaf(W10, cv[corner_cell(O, j, 1, 0)], v);
      if constexpr (W11 != 0.0f) v = fmaf(W11, cv[corner_cell(O, j, 1, 1)], v);
      acc = DIL ? fmaxf(acc, v) : fminf(acc, v);
    });
  }
  return acc;
}

template<int DIL>
__global__ void morph_kernel(const float* __restrict__ in, float* __restrict__ out,
                             const Tables* __restrict__ T) {
  int idx = blockIdx.x*256 + threadIdx.x;
  int w = idx & 127;
  int h = (idx >> 7) & 127;
  int o = (idx >> 14) & 7;
  int c = (idx >> 17) & 7;
  int b = idx >> 20;
  const float* base = in + b*BATCH_STR + c*CH_STR;
  const float* kt = (DIL ? T->kdil[c] : T->kero[c]);
  float acc;
  switch (o) {
    case 0: acc = morph_body<0, DIL>(base, kt, h, w); break;
    case 1: acc = morph_body<1, DIL>(base, kt, h, w); break;
    case 2: acc = morph_body<2, DIL>(base, kt, h, w); break;
    case 3: acc = morph_body<3, DIL>(base, kt, h, w); break;
    case 4: acc = morph_body<4, DIL>(base, kt, h, w); break;
    case 5: acc = morph_body<5, DIL>(base, kt, h, w); break;
    case 6: acc = morph_body<6, DIL>(base, kt, h, w); break;
    default: acc = morph_body<7, DIL>(base, kt, h, w); break;
  }
  out[idx] = acc;
}

__global__ void gram_kernel(const float* __restrict__ u, double* __restrict__ part) {
  double S[8];
  double G[36];
  #pragma unroll
  for (int i = 0; i < 8; i++) S[i] = 0.0;
  #pragma unroll
  for (int i = 0; i < 36; i++) G[i] = 0.0;
  for (int p = blockIdx.x*256 + threadIdx.x; p < NPOS; p += NB_RED*256) {
    int hw = p & 16383;
    int o  = (p >> 14) & 7;
    int b  = p >> 17;
    const float* base = u + b*BATCH_STR + o*PLANE + hw;
    float v[8];
    #pragma unroll
    for (int c = 0; c < 8; c++) v[c] = base[c*CH_STR];
    int t = 0;
    #pragma unroll
    for (int c = 0; c < 8; c++) {
      S[c] += (double)v[c];
      #pragma unroll
      for (int c2 = c; c2 < 8; c2++) { G[t] += (double)v[c]*(double)v[c2]; t++; }
    }
  }
  __shared__ double lds[4][44];
  int lane = threadIdx.x & 63;
  int wave = threadIdx.x >> 6;
  for (int t = 0; t < 44; t++) {
    double v = (t < 8) ? S[t] : G[t-8];
    for (int off = 32; off; off >>= 1) v += __shfl_down(v, off);
    if (lane == 0) lds[wave][t] = v;
  }
  __syncthreads();
  if (threadIdx.x < 44) {
    part[blockIdx.x*44 + threadIdx.x] =
      lds[0][threadIdx.x] + lds[1][threadIdx.x] + lds[2][threadIdx.x] + lds[3][threadIdx.x];
  }
}

__global__ void stats_kernel(const double* __restrict__ part, const float* __restrict__ weight,
                             const float* __restrict__ gamma, const float* __restrict__ beta,
                             float* __restrict__ ss) {
  __shared__ double tot[44];
  int t = threadIdx.x;
  if (t < 44) {
    double s = 0.0;
    for (int bidx = 0; bidx < NB_RED; bidx++) s += part[bidx*44 + t];
    tot[t] = s;
  }
  __syncthreads();
  if (t < 16) {
    double m = 0.0;
    for (int c = 0; c < 8; c++) m += (double)weight[c*COUT + t] * tot[c];
    double e2 = 0.0;
    int idx = 8;
    for (int c = 0; c < 8; c++)
      for (int c2 = c; c2 < 8; c2++) {
        double wp = (double)weight[c*COUT + t] * (double)weight[c2*COUT + t];
        e2 += (c2 == c ? 1.0 : 2.0) * wp * tot[idx];
        idx++;
      }
    double N = (double)NPOS;
    m /= N; e2 /= N;
    double var = e2 - m*m;
    double inv = rsqrt(var + 1e-5);
    float sc = (float)(inv * (double)gamma[t]);
    ss[t]      = sc;
    ss[16 + t] = beta[t] - (float)m * sc;
  }
}

__global__ void final_kernel(const float* __restrict__ u, const float* __restrict__ weight,
                             const float* __restrict__ ss, float* __restrict__ out) {
  __shared__ float Wsh[8][16];
  __shared__ float scale[16], shift[16];
  int t = threadIdx.x;
  if (t < 128) Wsh[t >> 4][t & 15] = weight[t];
  if (t < 16) { scale[t] = ss[t]; shift[t] = ss[16 + t]; }
  __syncthreads();
  int p = blockIdx.x*256 + threadIdx.x;
  int hw = p & 16383;
  int o  = (p >> 14) & 7;
  int b  = p >> 17;
  const float* base = u + b*BATCH_STR + o*PLANE + hw;
  float v[8];
  #pragma unroll
  for (int c = 0; c < 8; c++) v[c] = base[c*CH_STR];
  float* ob = out + b*(COUT*CH_STR) + o*PLANE + hw;
  #pragma unroll
  for (int d = 0; d < 16; d++) {
    float y = 0.f;
    #pragma unroll
    for (int c = 0; c < 8; c++) y = fmaf(v[c], Wsh[c][d], y);
    ob[d*CH_STR] = fmaf(y, scale[d], shift[d]);
  }
}

extern "C" void kernel_launch(void* const* d_in, const int* in_sizes, int n_in,
                              void* d_out, int out_size, void* d_ws, size_t ws_size,
                              hipStream_t stream) {
  const float* x      = (const float*)d_in[0];
  const float* g0     = (const float*)d_in[1];
  const float* mdil   = (const float*)d_in[2];
  const float* mero   = (const float*)d_in[3];
  const float* weight = (const float*)d_in[4];
  const float* gamma  = (const float*)d_in[5];
  const float* beta   = (const float*)d_in[6];
  float* out = (float*)d_out;

  char* ws = (char*)d_ws;
  Tables* T   = (Tables*)ws;                    // ~2 KB
  float*  ss  = (float*)(ws + 8*1024);          // 32 floats
  double* part = (double*)(ws + 16*1024);       // 512*44*8 = 180 KB
  float*  u3  = (float*)(ws + 1024*1024);       // 16 MiB

  float* u1 = out;          // first half of d_out as scratch
  float* u2 = out + NELEM;  // second half of d_out as scratch

  precompute_kernel<<<1, 1024, 0, stream>>>(g0, mdil, mero, T);
  conv_kernel<<<NELEM/256, 256, 0, stream>>>(x, u1, T);
  morph_kernel<1><<<NELEM/256, 256, 0, stream>>>(u1, u2, T);
  morph_kernel<0><<<NELEM/256, 256, 0, stream>>>(u2, u3, T);
  gram_kernel<<<NB_RED, 256, 0, stream>>>(u3, part);
  stats_kernel<<<1, 64, 0, stream>>>(part, weight, gamma, beta, ss);
  final_kernel<<<NPOS/256, 256, 0, stream>>>(u3, weight, ss, out);
}

// Round 3
// 128.102 us; speedup vs baseline: 1.8214x; 1.1753x over previous
//
#include <hip/hip_runtime.h>
#include <math.h>
#include <utility>

#define B 4
#define CIN 8
#define COUT 16
#define OR_ 8
#define H_ 128
#define W_ 128
#define HW 16384
#define PLANE HW
#define CH_STR (OR_*HW)        // 131072
#define BATCH_STR (CIN*CH_STR) // 1048576
#define NELEM (B*BATCH_STR)    // 4194304
#define NPOS (B*OR_*HW)        // 524288
#define NB_RED 512

// padded plane: 2-halo on all sides, rows/cols -2..129
#define PROW 132
#define PPLANE (132*132)       // 17424
#define NPLANES (B*CIN*OR_)    // 512
#define PAD_CELLS 1040         // 132*132 - 128*128 per plane

typedef __attribute__((ext_vector_type(4))) float f4;
typedef __attribute__((ext_vector_type(2))) float f2;

struct Tables {
  float kdil[CIN][27];
  float kero[CIN][27];
  int   conv_i[CIN];
  float conv_f[CIN];
  float conv_dy[CIN][OR_];
  float conv_dx[CIN][OR_];
};

// ---------------- compile-time tap geometry for morph ----------------
__host__ __device__ constexpr double m_cos(int o) {
  const double r = 0.70710678118654752440;
  const double t[8] = {1.0, r, 0.0, -r, -1.0, -r, 0.0, r};
  return t[o];
}
__host__ __device__ constexpr double m_sin(int o) {
  const double r = 0.70710678118654752440;
  const double t[8] = {0.0, r, 1.0, r, 0.0, -r, -1.0, -r};
  return t[o];
}
// j = (qy+1)*3 + (qx+1)
__host__ __device__ constexpr double tap_dx(int o, int j) {
  return m_cos(o)*(j % 3 - 1) - m_sin(o)*(j / 3 - 1);
}
__host__ __device__ constexpr double tap_dy(int o, int j) {
  return m_sin(o)*(j % 3 - 1) + m_cos(o)*(j / 3 - 1);
}
__host__ __device__ constexpr int ifloor(double v) {
  int i = (int)v;
  return ((double)i > v) ? i - 1 : i;
}
__host__ __device__ constexpr int tap_ix(int o, int j) { return ifloor(tap_dx(o, j)); } // [-2,1]
__host__ __device__ constexpr int tap_iy(int o, int j) { return ifloor(tap_dy(o, j)); }
__host__ __device__ constexpr float tap_fx(int o, int j) { return (float)(tap_dx(o, j) - tap_ix(o, j)); }
__host__ __device__ constexpr float tap_fy(int o, int j) { return (float)(tap_dy(o, j) - tap_iy(o, j)); }
__host__ __device__ constexpr float corner_w(int o, int j, int dyb, int dxb) {
  float fy = tap_fy(o, j), fx = tap_fx(o, j);
  return (dyb ? fy : 1.0f - fy) * (dxb ? fx : 1.0f - fx);
}
// window row (0..4) of a corner
__host__ __device__ constexpr int corner_r(int o, int j, int dyb) { return tap_iy(o, j) + dyb + 2; }
// window col (0..7) of a corner for output pixel i (0..3)
__host__ __device__ constexpr int corner_c(int o, int j, int i, int dxb) { return i + tap_ix(o, j) + dxb + 2; }
__host__ __device__ constexpr bool row_used(int o, int r) {
  for (int j = 0; j < 9; ++j)
    for (int dyb = 0; dyb < 2; ++dyb)
      for (int dxb = 0; dxb < 2; ++dxb)
        if (corner_w(o, j, dyb, dxb) != 0.0f && corner_r(o, j, dyb) == r)
          return true;
  return false;
}

template<int N> struct Rep {
  template<class F> __device__ __forceinline__ static void run(F&& f) {
    Rep<N-1>::run(f);
    f(std::integral_constant<int, N-1>{});
  }
};
template<> struct Rep<0> {
  template<class F> __device__ __forceinline__ static void run(F&&) {}
};

// ---------------- kernels ----------------

__global__ void precompute_kernel(const float* __restrict__ g0,
                                  const float* __restrict__ mdil,
                                  const float* __restrict__ mero,
                                  Tables* __restrict__ T) {
  const int t = threadIdx.x;
  const double TWO_PI = 6.283185307179586476925286766559;
  const double P  = 2.0*0.65/(2.0*0.65 - 1.0);
  const double NU = (2.0*0.65 - 1.0)*pow(2.0*0.65, -P);
  if (t < 432) {
    int which = t / 216;           // 0 = dilate, 1 = erode
    int r = t % 216;
    int c = r / 27;
    int j = r % 27;                // j = (qt+1)*9 + (qy+1)*3 + (qx+1)
    int qt = j/9 - 1;
    int qy = (j/3)%3 - 1;
    int qx = j%3 - 1;
    double dth = qt * (TWO_PI/OR_);
    double c1, c2, c3;
    if (qt == 0) { c1 = qx; c2 = qy; c3 = 0.0; }
    else {
      double h = 0.5*dth;
      double cot = cos(h)/sin(h);
      c1 = h*(qx*cot + qy);
      c2 = h*(-qx + qy*cot);
      c3 = dth;
    }
    const float* m = which ? mero : mdil;
    double a0 = (double)m[c*3+0]*c1;
    double a1 = (double)m[c*3+1]*c2;
    double a2 = (double)m[c*3+2]*c3;
    double s = a0*a0 + a1*a1 + a2*a2;
    float k = (float)(NU * pow(s, P*0.5));
    if (which) T->kero[c][j] = k; else T->kdil[c][j] = k;
  } else if (t >= 512 && t < 512 + CIN*OR_) {
    int r = t - 512;
    int c = r / OR_;
    int o = r % OR_;
    float x0 = g0[c*3+0], y0 = g0[c*3+1], th0 = g0[c*3+2];
    float a = (float)(o*(TWO_PI/OR_)) - th0;
    float ca = cosf(a), sa = sinf(a);
    T->conv_dx[c][o] = -(ca*x0 - sa*y0);
    T->conv_dy[c][o] = -(sa*x0 + ca*y0);
    if (o == 0) {
      float tt = th0 * (float)(OR_/TWO_PI);
      float fi = floorf(tt);
      T->conv_i[c] = (int)fi;
      T->conv_f[c] = tt - fi;
    }
  }
}

// conv: unchanged math, but writes into the PADDED layout (interior only)
__global__ void conv_kernel(const float* __restrict__ x, float* __restrict__ out,
                            const Tables* __restrict__ T) {
  int idx = blockIdx.x*256 + threadIdx.x;
  int w = idx & 127;
  int h = (idx >> 7) & 127;
  int o = (idx >> 14) & 7;
  int c = (idx >> 17) & 7;
  int b = idx >> 20;
  int i = T->conv_i[c];
  float f = T->conv_f[c];
  int o1 = (o - i) & 7;
  int o2 = (o - i - 1) & 7;
  const float* p1 = x + b*BATCH_STR + c*CH_STR + o1*PLANE;
  const float* p2 = x + b*BATCH_STR + c*CH_STR + o2*PLANE;
  float dy = T->conv_dy[c][o], dx = T->conv_dx[c][o];
  float fy0 = floorf(dy); float fy = dy - fy0;
  float fx0 = floorf(dx); float fx = dx - fx0;
  int iy = h + (int)fy0;
  int ix = w + (int)fx0;
  int r0 = min(max(iy, 0), 127), r1 = min(max(iy+1, 0), 127);
  int c0 = min(max(ix, 0), 127), c1 = min(max(ix+1, 0), 127);
  float w00 = (1.f-fy)*(1.f-fx), w01 = (1.f-fy)*fx, w10 = fy*(1.f-fx), w11 = fy*fx;
  float v1 = w00*p1[r0*W_+c0] + w01*p1[r0*W_+c1] + w10*p1[r1*W_+c0] + w11*p1[r1*W_+c1];
  float v2 = w00*p2[r0*W_+c0] + w01*p2[r0*W_+c1] + w10*p2[r1*W_+c0] + w11*p2[r1*W_+c1];
  int pl = ((b*CIN + c)*OR_ + o);
  out[pl*PPLANE + (h+2)*PROW + (w+2)] = (1.0f - f)*v1 + f*v2;
}

// fill the 2-halo of every padded plane with edge-replicated (clamped) values
__global__ void pad_kernel(float* __restrict__ t) {
  int i = blockIdx.x*256 + threadIdx.x;
  if (i >= NPLANES*PAD_CELLS) return;
  int plane = i / PAD_CELLS;
  int r = i - plane*PAD_CELLS;
  int pr, pc;
  if (r < 4*PROW) {
    int rr = r / PROW;
    pc = r - rr*PROW;
    pr = (rr < 2) ? rr : rr + 128;     // rows 0,1,130,131 full width
  } else {
    int j = r - 4*PROW;
    pr = 2 + (j >> 2);                  // rows 2..129
    int cc = j & 3;
    pc = (cc < 2) ? cc : cc + 128;      // cols 0,1,130,131
  }
  int lh = min(max(pr - 2, 0), 127);
  int lw = min(max(pc - 2, 0), 127);
  float v = t[plane*PPLANE + (lh+2)*PROW + (lw+2)];
  t[plane*PPLANE + pr*PROW + pc] = v;
}

// morph inner: one source orientation plane, 4 outputs, window in registers.
// prow0 points at padded (h-2, w0-2); kq = 9 kernel values for this qt.
template<int O, int DIL>
__device__ __forceinline__ void morph_plane(const float* __restrict__ prow0,
                                            const float* __restrict__ kq,
                                            float acc[4]) {
  float win[5][8];
  Rep<5>::run([&](auto rc) {
    constexpr int r = decltype(rc)::value;
    if constexpr (row_used(O, r)) {
      const f4* p = (const f4*)(prow0 + r*PROW);
      f4 lo = p[0], hi = p[1];
      win[r][0] = lo.x; win[r][1] = lo.y; win[r][2] = lo.z; win[r][3] = lo.w;
      win[r][4] = hi.x; win[r][5] = hi.y; win[r][6] = hi.z; win[r][7] = hi.w;
    }
  });
  Rep<9>::run([&](auto jc) {
    constexpr int j = decltype(jc)::value;
    float k = kq[j];
    float base = DIL ? -k : k;
    Rep<4>::run([&](auto ic) {
      constexpr int i = decltype(ic)::value;
      float v = base;
      Rep<4>::run([&](auto cc2) {
        constexpr int cn  = decltype(cc2)::value;
        constexpr int dyb = cn >> 1, dxb = cn & 1;
        constexpr float Wgt = corner_w(O, j, dyb, dxb);
        if constexpr (Wgt != 0.0f) {
          constexpr int R = corner_r(O, j, dyb);
          constexpr int C = corner_c(O, j, i, dxb);
          v = fmaf(Wgt, win[R][C], v);
        }
      });
      acc[i] = DIL ? fmaxf(acc[i], v) : fminf(acc[i], v);
    });
  });
}

template<int O, int DIL>
__device__ __forceinline__ void morph_body4(const float* __restrict__ base,
                                            const float* __restrict__ kt,
                                            int h, int w0, float acc[4]) {
  Rep<3>::run([&](auto qc) {
    constexpr int qti = decltype(qc)::value;
    const float* plane = base + ((O + qti + 7) & 7) * PPLANE;
    morph_plane<O, DIL>(plane + h*PROW + w0, kt + qti*9, acc);
  });
}

// DIL=1: padded in -> padded out (dilate). DIL=0: padded in -> linear out (erode).
template<int DIL>
__global__ void morph_kernel(const float* __restrict__ in, float* __restrict__ out,
                             const Tables* __restrict__ T) {
  int i4 = blockIdx.x*256 + threadIdx.x;     // NELEM/4 threads
  int w0 = (i4 & 31) << 2;
  int h  = (i4 >> 5) & 127;
  int o  = (i4 >> 12) & 7;
  int c  = (i4 >> 15) & 7;
  int b  = i4 >> 18;
  const float* base = in + (b*CIN + c)*(OR_*PPLANE);
  const float* kt = DIL ? T->kdil[c] : T->kero[c];
  float acc[4];
  #pragma unroll
  for (int i = 0; i < 4; ++i) acc[i] = DIL ? -INFINITY : INFINITY;
  switch (o) {
    case 0: morph_body4<0, DIL>(base, kt, h, w0, acc); break;
    case 1: morph_body4<1, DIL>(base, kt, h, w0, acc); break;
    case 2: morph_body4<2, DIL>(base, kt, h, w0, acc); break;
    case 3: morph_body4<3, DIL>(base, kt, h, w0, acc); break;
    case 4: morph_body4<4, DIL>(base, kt, h, w0, acc); break;
    case 5: morph_body4<5, DIL>(base, kt, h, w0, acc); break;
    case 6: morph_body4<6, DIL>(base, kt, h, w0, acc); break;
    default: morph_body4<7, DIL>(base, kt, h, w0, acc); break;
  }
  if (DIL) {
    float* dst = out + ((b*CIN + c)*OR_ + o)*PPLANE + (h+2)*PROW + (w0+2);
    f2 a = {acc[0], acc[1]}, bb = {acc[2], acc[3]};
    *(f2*)dst = a;
    *(f2*)(dst + 2) = bb;
  } else {
    float* dst = out + (((b*CIN + c)*OR_ + o)*PLANE) + h*W_ + w0;
    f4 v = {acc[0], acc[1], acc[2], acc[3]};
    *(f4*)dst = v;
  }
}

__global__ void gram_kernel(const float* __restrict__ u, double* __restrict__ part) {
  int t4 = blockIdx.x*256 + threadIdx.x;     // NPOS/4 = 131072 threads
  int hw = (t4 & 4095) << 2;
  int o  = (t4 >> 12) & 7;
  int b  = t4 >> 15;
  const float* base = u + b*BATCH_STR + o*PLANE + hw;
  f4 v[8];
  #pragma unroll
  for (int c = 0; c < 8; c++) v[c] = *(const f4*)(base + c*CH_STR);
  float S[8], G[36];
  #pragma unroll
  for (int c = 0; c < 8; c++) S[c] = v[c].x + v[c].y + v[c].z + v[c].w;
  {
    int t = 0;
    #pragma unroll
    for (int c = 0; c < 8; c++)
      #pragma unroll
      for (int c2 = c; c2 < 8; c2++) {
        G[t] = v[c].x*v[c2].x + v[c].y*v[c2].y + v[c].z*v[c2].z + v[c].w*v[c2].w;
        t++;
      }
  }
  __shared__ double lds[4][44];
  int lane = threadIdx.x & 63;
  int wave = threadIdx.x >> 6;
  for (int t = 0; t < 44; t++) {
    double vv = (double)((t < 8) ? S[t] : G[t-8]);
    for (int off = 32; off; off >>= 1) vv += __shfl_down(vv, off);
    if (lane == 0) lds[wave][t] = vv;
  }
  __syncthreads();
  if (threadIdx.x < 44) {
    part[blockIdx.x*44 + threadIdx.x] =
      lds[0][threadIdx.x] + lds[1][threadIdx.x] + lds[2][threadIdx.x] + lds[3][threadIdx.x];
  }
}

__global__ void stats_kernel(const double* __restrict__ part, const float* __restrict__ weight,
                             const float* __restrict__ gamma, const float* __restrict__ beta,
                             float* __restrict__ ss) {
  __shared__ double tot[44];
  int t = threadIdx.x;
  if (t < 44) {
    double s = 0.0;
    for (int bidx = 0; bidx < NB_RED; bidx++) s += part[bidx*44 + t];
    tot[t] = s;
  }
  __syncthreads();
  if (t < 16) {
    double m = 0.0;
    for (int c = 0; c < 8; c++) m += (double)weight[c*COUT + t] * tot[c];
    double e2 = 0.0;
    int idx = 8;
    for (int c = 0; c < 8; c++)
      for (int c2 = c; c2 < 8; c2++) {
        double wp = (double)weight[c*COUT + t] * (double)weight[c2*COUT + t];
        e2 += (c2 == c ? 1.0 : 2.0) * wp * tot[idx];
        idx++;
      }
    double N = (double)NPOS;
    m /= N; e2 /= N;
    double var = e2 - m*m;
    double inv = rsqrt(var + 1e-5);
    float sc = (float)(inv * (double)gamma[t]);
    ss[t]      = sc;
    ss[16 + t] = beta[t] - (float)m * sc;
  }
}

__global__ void final_kernel(const float* __restrict__ u, const float* __restrict__ weight,
                             const float* __restrict__ ss, float* __restrict__ out) {
  __shared__ float Wsh[8][16];
  __shared__ float scale[16], shift[16];
  int t = threadIdx.x;
  if (t < 128) Wsh[t >> 4][t & 15] = weight[t];
  if (t < 16) { scale[t] = ss[t]; shift[t] = ss[16 + t]; }
  __syncthreads();
  int t4 = blockIdx.x*256 + threadIdx.x;     // 131072 threads
  int hw = (t4 & 4095) << 2;
  int o  = (t4 >> 12) & 7;
  int b  = t4 >> 15;
  const float* base = u + b*BATCH_STR + o*PLANE + hw;
  f4 v[8];
  #pragma unroll
  for (int c = 0; c < 8; c++) v[c] = *(const f4*)(base + c*CH_STR);
  float* ob = out + b*(COUT*CH_STR) + o*PLANE + hw;
  #pragma unroll
  for (int d = 0; d < 16; d++) {
    f4 y = {0.f, 0.f, 0.f, 0.f};
    #pragma unroll
    for (int c = 0; c < 8; c++) {
      float wv = Wsh[c][d];
      y.x = fmaf(v[c].x, wv, y.x);
      y.y = fmaf(v[c].y, wv, y.y);
      y.z = fmaf(v[c].z, wv, y.z);
      y.w = fmaf(v[c].w, wv, y.w);
    }
    float sc = scale[d], sh = shift[d];
    f4 r = { fmaf(y.x, sc, sh), fmaf(y.y, sc, sh), fmaf(y.z, sc, sh), fmaf(y.w, sc, sh) };
    *(f4*)(ob + d*CH_STR) = r;
  }
}

extern "C" void kernel_launch(void* const* d_in, const int* in_sizes, int n_in,
                              void* d_out, int out_size, void* d_ws, size_t ws_size,
                              hipStream_t stream) {
  const float* x      = (const float*)d_in[0];
  const float* g0     = (const float*)d_in[1];
  const float* mdil   = (const float*)d_in[2];
  const float* mero   = (const float*)d_in[3];
  const float* weight = (const float*)d_in[4];
  const float* gamma  = (const float*)d_in[5];
  const float* beta   = (const float*)d_in[6];
  float* out = (float*)d_out;

  char* ws = (char*)d_ws;
  Tables* T    = (Tables*)ws;                         // ~2 KB
  float*  ss   = (float*)(ws + 8*1024);               // 32 floats
  double* part = (double*)(ws + 16*1024);             // 512*44*8 = 180 KB
  float*  u1p  = (float*)(ws + (size_t)1*1024*1024);  // padded, 35.7 MB
  float*  u2p  = (float*)(ws + (size_t)40*1024*1024); // padded, 35.7 MB
  float*  u3   = (float*)(ws + (size_t)80*1024*1024); // linear, 16 MB

  const int padBlocks = (NPLANES*PAD_CELLS + 255)/256;

  precompute_kernel<<<1, 1024, 0, stream>>>(g0, mdil, mero, T);
  conv_kernel<<<NELEM/256, 256, 0, stream>>>(x, u1p, T);
  pad_kernel<<<padBlocks, 256, 0, stream>>>(u1p);
  morph_kernel<1><<<NELEM/4/256, 256, 0, stream>>>(u1p, u2p, T);
  pad_kernel<<<padBlocks, 256, 0, stream>>>(u2p);
  morph_kernel<0><<<NELEM/4/256, 256, 0, stream>>>(u2p, u3, T);
  gram_kernel<<<NB_RED, 256, 0, stream>>>(u3, part);
  stats_kernel<<<1, 64, 0, stream>>>(part, weight, gamma, beta, ss);
  final_kernel<<<NPOS/4/256, 256, 0, stream>>>(u3, weight, ss, out);
}

// Round 4
// 119.487 us; speedup vs baseline: 1.9527x; 1.0721x over previous
//
#include <hip/hip_runtime.h>
#include <math.h>
#include <utility>

#define B 4
#define CIN 8
#define COUT 16
#define OR_ 8
#define H_ 128
#define W_ 128
#define HW 16384
#define PLANE HW
#define CH_STR (OR_*HW)        // 131072
#define BATCH_STR (CIN*CH_STR) // 1048576
#define NELEM (B*BATCH_STR)    // 4194304
#define NPOS (B*OR_*HW)        // 524288
#define NB_RED 512

// fused tiling
#define TILE 16
#define CB_DIM 24              // conv buffer rows/cols (tile + 2*4 halo)
#define CB_S   28              // conv buffer row stride (floats, mult of 4)
#define CB_PL  (CB_DIM*CB_S)   // 672 floats per orientation
#define DB_DIM 20              // dilate buffer rows/cols (tile + 2*2 halo)
#define DB_S   28
#define DB_PL  (DB_DIM*DB_S)   // 560

typedef __attribute__((ext_vector_type(4))) float f4;

struct Tables {
  float kdil[CIN][27];
  float kero[CIN][27];
  int   conv_i[CIN];
  float conv_f[CIN];
  float conv_dy[CIN][OR_];
  float conv_dx[CIN][OR_];
};

// ---------------- compile-time tap geometry ----------------
__host__ __device__ constexpr double m_cos(int o) {
  const double r = 0.70710678118654752440;
  const double t[8] = {1.0, r, 0.0, -r, -1.0, -r, 0.0, r};
  return t[o];
}
__host__ __device__ constexpr double m_sin(int o) {
  const double r = 0.70710678118654752440;
  const double t[8] = {0.0, r, 1.0, r, 0.0, -r, -1.0, -r};
  return t[o];
}
// j = (qy+1)*3 + (qx+1)
__host__ __device__ constexpr double tap_dx(int o, int j) {
  return m_cos(o)*(j % 3 - 1) - m_sin(o)*(j / 3 - 1);
}
__host__ __device__ constexpr double tap_dy(int o, int j) {
  return m_sin(o)*(j % 3 - 1) + m_cos(o)*(j / 3 - 1);
}
__host__ __device__ constexpr int ifloor(double v) {
  int i = (int)v;
  return ((double)i > v) ? i - 1 : i;
}
__host__ __device__ constexpr int tap_ix(int o, int j) { return ifloor(tap_dx(o, j)); } // [-2,1]
__host__ __device__ constexpr int tap_iy(int o, int j) { return ifloor(tap_dy(o, j)); }
__host__ __device__ constexpr float tap_fx(int o, int j) { return (float)(tap_dx(o, j) - tap_ix(o, j)); }
__host__ __device__ constexpr float tap_fy(int o, int j) { return (float)(tap_dy(o, j) - tap_iy(o, j)); }
__host__ __device__ constexpr float corner_w(int o, int j, int dyb, int dxb) {
  float fy = tap_fy(o, j), fx = tap_fx(o, j);
  return (dyb ? fy : 1.0f - fy) * (dxb ? fx : 1.0f - fx);
}
__host__ __device__ constexpr int corner_r(int o, int j, int dyb) { return tap_iy(o, j) + dyb + 2; } // 0..4
__host__ __device__ constexpr int corner_c(int o, int j, int i, int dxb) { return i + tap_ix(o, j) + dxb + 2; } // 0..7
__host__ __device__ constexpr bool row_used(int o, int r) {
  for (int j = 0; j < 9; ++j)
    for (int dyb = 0; dyb < 2; ++dyb)
      for (int dxb = 0; dxb < 2; ++dxb)
        if (corner_w(o, j, dyb, dxb) != 0.0f && corner_r(o, j, dyb) == r)
          return true;
  return false;
}

template<int N> struct Rep {
  template<class F> __device__ __forceinline__ static void run(F&& f) {
    Rep<N-1>::run(f);
    f(std::integral_constant<int, N-1>{});
  }
};
template<> struct Rep<0> {
  template<class F> __device__ __forceinline__ static void run(F&&) {}
};

// ---------------- kernels ----------------

__global__ void precompute_kernel(const float* __restrict__ g0,
                                  const float* __restrict__ mdil,
                                  const float* __restrict__ mero,
                                  Tables* __restrict__ T) {
  const int t = threadIdx.x;
  const double TWO_PI = 6.283185307179586476925286766559;
  const double P  = 2.0*0.65/(2.0*0.65 - 1.0);
  const double NU = (2.0*0.65 - 1.0)*pow(2.0*0.65, -P);
  if (t < 432) {
    int which = t / 216;           // 0 = dilate, 1 = erode
    int r = t % 216;
    int c = r / 27;
    int j = r % 27;                // j = (qt+1)*9 + (qy+1)*3 + (qx+1)
    int qt = j/9 - 1;
    int qy = (j/3)%3 - 1;
    int qx = j%3 - 1;
    double dth = qt * (TWO_PI/OR_);
    double c1, c2, c3;
    if (qt == 0) { c1 = qx; c2 = qy; c3 = 0.0; }
    else {
      double h = 0.5*dth;
      double cot = cos(h)/sin(h);
      c1 = h*(qx*cot + qy);
      c2 = h*(-qx + qy*cot);
      c3 = dth;
    }
    const float* m = which ? mero : mdil;
    double a0 = (double)m[c*3+0]*c1;
    double a1 = (double)m[c*3+1]*c2;
    double a2 = (double)m[c*3+2]*c3;
    double s = a0*a0 + a1*a1 + a2*a2;
    float k = (float)(NU * pow(s, P*0.5));
    if (which) T->kero[c][j] = k; else T->kdil[c][j] = k;
  } else if (t >= 512 && t < 512 + CIN*OR_) {
    int r = t - 512;
    int c = r / OR_;
    int o = r % OR_;
    float x0 = g0[c*3+0], y0 = g0[c*3+1], th0 = g0[c*3+2];
    float a = (float)(o*(TWO_PI/OR_)) - th0;
    float ca = cosf(a), sa = sinf(a);
    T->conv_dx[c][o] = -(ca*x0 - sa*y0);
    T->conv_dy[c][o] = -(sa*x0 + ca*y0);
    if (o == 0) {
      float tt = th0 * (float)(OR_/TWO_PI);
      float fi = floorf(tt);
      T->conv_i[c] = (int)fi;
      T->conv_f[c] = tt - fi;
    }
  }
}

// morph window evaluation from an LDS source holding all 8 orientation planes.
// src + osrc*PLSTR + row*RSTR + gc points at window col 0 / row 0 for this group.
template<int O, int DIL, int PLSTR, int RSTR>
__device__ __forceinline__ void morph_tile_lds(const float* __restrict__ src,
                                               const float* __restrict__ kt,
                                               int row, int gc, float acc[4]) {
  Rep<3>::run([&](auto qc) {
    constexpr int qti = decltype(qc)::value;
    const float* p = src + ((O + qti + 7) & 7) * PLSTR + row * RSTR + gc;
    float win[5][8];
    Rep<5>::run([&](auto rc) {
      constexpr int r = decltype(rc)::value;
      if constexpr (row_used(O, r)) {
        f4 lo = *(const f4*)(p + r*RSTR);
        f4 hi = *(const f4*)(p + r*RSTR + 4);
        win[r][0] = lo.x; win[r][1] = lo.y; win[r][2] = lo.z; win[r][3] = lo.w;
        win[r][4] = hi.x; win[r][5] = hi.y; win[r][6] = hi.z; win[r][7] = hi.w;
      }
    });
    Rep<9>::run([&](auto jc) {
      constexpr int j = decltype(jc)::value;
      float k = kt[qti*9 + j];
      float base = DIL ? -k : k;
      Rep<4>::run([&](auto ic) {
        constexpr int i = decltype(ic)::value;
        float v = base;
        Rep<4>::run([&](auto cc2) {
          constexpr int cn  = decltype(cc2)::value;
          constexpr int dyb = cn >> 1, dxb = cn & 1;
          constexpr float Wgt = corner_w(O, j, dyb, dxb);
          if constexpr (Wgt != 0.0f) {
            constexpr int R = corner_r(O, j, dyb);
            constexpr int C = corner_c(O, j, i, dxb);
            v = fmaf(Wgt, win[R][C], v);
          }
        });
        acc[i] = DIL ? fmaxf(acc[i], v) : fminf(acc[i], v);
      });
    });
  });
}

template<int O>
__device__ __forceinline__ void dil_wave(const float* __restrict__ cb, float* __restrict__ db,
                                         const float* __restrict__ kt, int lane) {
  #pragma unroll
  for (int it = 0; it < 2; ++it) {
    int g = lane + it*64;
    if (g < 100) {
      int row = g / 5;
      int gc = (g - row*5) * 4;
      float acc[4] = {-INFINITY, -INFINITY, -INFINITY, -INFINITY};
      morph_tile_lds<O, 1, CB_PL, CB_S>(cb, kt, row, gc, acc);
      f4 v = {acc[0], acc[1], acc[2], acc[3]};
      *(f4*)(db + O*DB_PL + row*DB_S + gc) = v;
    }
  }
}

template<int O>
__device__ __forceinline__ void ero_wave(const float* __restrict__ db, float* __restrict__ dst,
                                         const float* __restrict__ kt, int lane) {
  int row = lane >> 2;
  int gc = (lane & 3) * 4;
  float acc[4] = {INFINITY, INFINITY, INFINITY, INFINITY};
  morph_tile_lds<O, 0, DB_PL, DB_S>(db, kt, row, gc, acc);
  f4 v = {acc[0], acc[1], acc[2], acc[3]};
  *(f4*)(dst + O*PLANE + row*W_ + gc) = v;
}

// conv -> dilate -> erode, one (b,c,16x16 tile) per block, 512 threads (8 waves).
__global__ __launch_bounds__(512, 4)
void fused_kernel(const float* __restrict__ x, float* __restrict__ u3,
                  const Tables* __restrict__ T) {
  __shared__ float convbuf[8*CB_PL];   // 5376 f = 21.5 KB
  __shared__ float dilbuf[8*DB_PL];    // 4480 f = 17.9 KB
  int blk = blockIdx.x;
  int tx = blk & 7, ty = (blk >> 3) & 7, c = (blk >> 6) & 7, b = blk >> 9;
  int h0 = ty*TILE, w0 = tx*TILE;
  int t = threadIdx.x;
  int wid = t >> 6, lane = t & 63;

  // ---- stage 1: convection into convbuf, evaluated at clamped coords ----
  const int   ci = T->conv_i[c];
  const float cf = T->conv_f[c];
  const float* xc = x + b*BATCH_STR + c*CH_STR;
  #pragma unroll
  for (int k = 0; k < 9; ++k) {
    int cc = t + k*512;                  // < 4608 = 8*24*24
    int col = cc % CB_DIM;
    int tmp = cc / CB_DIM;
    int r = tmp % CB_DIM;
    int o = tmp / CB_DIM;
    int gh = min(max(h0 - 4 + r, 0), 127);
    int gw = min(max(w0 - 4 + col, 0), 127);
    int o1 = (o - ci) & 7, o2 = (o - ci - 1) & 7;
    const float* p1 = xc + o1*PLANE;
    const float* p2 = xc + o2*PLANE;
    float dy = T->conv_dy[c][o], dx = T->conv_dx[c][o];
    float fy0 = floorf(dy); float fy = dy - fy0;
    float fx0 = floorf(dx); float fx = dx - fx0;
    int iy = gh + (int)fy0;
    int ix = gw + (int)fx0;
    int r0 = min(max(iy, 0), 127), r1 = min(max(iy+1, 0), 127);
    int c0 = min(max(ix, 0), 127), c1 = min(max(ix+1, 0), 127);
    float w00 = (1.f-fy)*(1.f-fx), w01 = (1.f-fy)*fx, w10 = fy*(1.f-fx), w11 = fy*fx;
    float v1 = w00*p1[r0*W_+c0] + w01*p1[r0*W_+c1] + w10*p1[r1*W_+c0] + w11*p1[r1*W_+c1];
    float v2 = w00*p2[r0*W_+c0] + w01*p2[r0*W_+c1] + w10*p2[r1*W_+c0] + w11*p2[r1*W_+c1];
    convbuf[(o*CB_DIM + r)*CB_S + col] = (1.0f - cf)*v1 + cf*v2;
  }
  __syncthreads();

  // ---- stage 2: dilate into dilbuf (per-wave-uniform orientation) ----
  {
    const float* kt = T->kdil[c];
    switch (wid) {
      case 0: dil_wave<0>(convbuf, dilbuf, kt, lane); break;
      case 1: dil_wave<1>(convbuf, dilbuf, kt, lane); break;
      case 2: dil_wave<2>(convbuf, dilbuf, kt, lane); break;
      case 3: dil_wave<3>(convbuf, dilbuf, kt, lane); break;
      case 4: dil_wave<4>(convbuf, dilbuf, kt, lane); break;
      case 5: dil_wave<5>(convbuf, dilbuf, kt, lane); break;
      case 6: dil_wave<6>(convbuf, dilbuf, kt, lane); break;
      default: dil_wave<7>(convbuf, dilbuf, kt, lane); break;
    }
  }
  __syncthreads();

  // ---- stage 2b: replicate dilbuf halo for edge tiles (clamped semantics) ----
  if ((h0 == 0) | (h0 == 112) | (w0 == 0) | (w0 == 112)) {
    #pragma unroll
    for (int k = 0; k < 7; ++k) {
      int cc = t + k*512;                // over 3200 = 8*20*20
      if (cc < 3200) {
        int col = cc % DB_DIM;
        int tmp = cc / DB_DIM;
        int row = tmp % DB_DIM;
        int o = tmp / DB_DIM;
        int vh = h0 - 2 + row, vw = w0 - 2 + col;
        int dr = min(max(vh, 0), 127) - vh;
        int dc = min(max(vw, 0), 127) - vw;
        if ((dr != 0) | (dc != 0)) {
          dilbuf[(o*DB_DIM + row)*DB_S + col] =
            dilbuf[(o*DB_DIM + row + dr)*DB_S + col + dc];
        }
      }
    }
  }
  __syncthreads();

  // ---- stage 3: erode -> u3 (linear) ----
  {
    const float* kt = T->kero[c];
    float* dst = u3 + (b*CIN + c)*(OR_*PLANE) + h0*W_ + w0;
    switch (wid) {
      case 0: ero_wave<0>(dilbuf, dst, kt, lane); break;
      case 1: ero_wave<1>(dilbuf, dst, kt, lane); break;
      case 2: ero_wave<2>(dilbuf, dst, kt, lane); break;
      case 3: ero_wave<3>(dilbuf, dst, kt, lane); break;
      case 4: ero_wave<4>(dilbuf, dst, kt, lane); break;
      case 5: ero_wave<5>(dilbuf, dst, kt, lane); break;
      case 6: ero_wave<6>(dilbuf, dst, kt, lane); break;
      default: ero_wave<7>(dilbuf, dst, kt, lane); break;
    }
  }
}

__global__ void gram_kernel(const float* __restrict__ u, double* __restrict__ part) {
  int t4 = blockIdx.x*256 + threadIdx.x;     // NPOS/4 = 131072 threads
  int hw = (t4 & 4095) << 2;
  int o  = (t4 >> 12) & 7;
  int b  = t4 >> 15;
  const float* base = u + b*BATCH_STR + o*PLANE + hw;
  f4 v[8];
  #pragma unroll
  for (int c = 0; c < 8; c++) v[c] = *(const f4*)(base + c*CH_STR);
  float S[8], G[36];
  #pragma unroll
  for (int c = 0; c < 8; c++) S[c] = v[c].x + v[c].y + v[c].z + v[c].w;
  {
    int t = 0;
    #pragma unroll
    for (int c = 0; c < 8; c++)
      #pragma unroll
      for (int c2 = c; c2 < 8; c2++) {
        G[t] = v[c].x*v[c2].x + v[c].y*v[c2].y + v[c].z*v[c2].z + v[c].w*v[c2].w;
        t++;
      }
  }
  __shared__ double lds[4][44];
  int lane = threadIdx.x & 63;
  int wave = threadIdx.x >> 6;
  for (int t = 0; t < 44; t++) {
    double vv = (double)((t < 8) ? S[t] : G[t-8]);
    for (int off = 32; off; off >>= 1) vv += __shfl_down(vv, off);
    if (lane == 0) lds[wave][t] = vv;
  }
  __syncthreads();
  if (threadIdx.x < 44) {
    part[blockIdx.x*44 + threadIdx.x] =
      lds[0][threadIdx.x] + lds[1][threadIdx.x] + lds[2][threadIdx.x] + lds[3][threadIdx.x];
  }
}

__global__ void stats_kernel(const double* __restrict__ part, const float* __restrict__ weight,
                             const float* __restrict__ gamma, const float* __restrict__ beta,
                             float* __restrict__ ss) {
  __shared__ double tot[44];
  int t = threadIdx.x;
  if (t < 44) {
    double s = 0.0;
    for (int bidx = 0; bidx < NB_RED; bidx++) s += part[bidx*44 + t];
    tot[t] = s;
  }
  __syncthreads();
  if (t < 16) {
    double m = 0.0;
    for (int c = 0; c < 8; c++) m += (double)weight[c*COUT + t] * tot[c];
    double e2 = 0.0;
    int idx = 8;
    for (int c = 0; c < 8; c++)
      for (int c2 = c; c2 < 8; c2++) {
        double wp = (double)weight[c*COUT + t] * (double)weight[c2*COUT + t];
        e2 += (c2 == c ? 1.0 : 2.0) * wp * tot[idx];
        idx++;
      }
    double N = (double)NPOS;
    m /= N; e2 /= N;
    double var = e2 - m*m;
    double inv = rsqrt(var + 1e-5);
    float sc = (float)(inv * (double)gamma[t]);
    ss[t]      = sc;
    ss[16 + t] = beta[t] - (float)m * sc;
  }
}

__global__ void final_kernel(const float* __restrict__ u, const float* __restrict__ weight,
                             const float* __restrict__ ss, float* __restrict__ out) {
  __shared__ float Wsh[8][16];
  __shared__ float scale[16], shift[16];
  int t = threadIdx.x;
  if (t < 128) Wsh[t >> 4][t & 15] = weight[t];
  if (t < 16) { scale[t] = ss[t]; shift[t] = ss[16 + t]; }
  __syncthreads();
  int t4 = blockIdx.x*256 + threadIdx.x;     // 131072 threads
  int hw = (t4 & 4095) << 2;
  int o  = (t4 >> 12) & 7;
  int b  = t4 >> 15;
  const float* base = u + b*BATCH_STR + o*PLANE + hw;
  f4 v[8];
  #pragma unroll
  for (int c = 0; c < 8; c++) v[c] = *(const f4*)(base + c*CH_STR);
  float* ob = out + b*(COUT*CH_STR) + o*PLANE + hw;
  #pragma unroll
  for (int d = 0; d < 16; d++) {
    f4 y = {0.f, 0.f, 0.f, 0.f};
    #pragma unroll
    for (int c = 0; c < 8; c++) {
      float wv = Wsh[c][d];
      y.x = fmaf(v[c].x, wv, y.x);
      y.y = fmaf(v[c].y, wv, y.y);
      y.z = fmaf(v[c].z, wv, y.z);
      y.w = fmaf(v[c].w, wv, y.w);
    }
    float sc = scale[d], sh = shift[d];
    f4 r = { fmaf(y.x, sc, sh), fmaf(y.y, sc, sh), fmaf(y.z, sc, sh), fmaf(y.w, sc, sh) };
    *(f4*)(ob + d*CH_STR) = r;
  }
}

extern "C" void kernel_launch(void* const* d_in, const int* in_sizes, int n_in,
                              void* d_out, int out_size, void* d_ws, size_t ws_size,
                              hipStream_t stream) {
  const float* x      = (const float*)d_in[0];
  const float* g0     = (const float*)d_in[1];
  const float* mdil   = (const float*)d_in[2];
  const float* mero   = (const float*)d_in[3];
  const float* weight = (const float*)d_in[4];
  const float* gamma  = (const float*)d_in[5];
  const float* beta   = (const float*)d_in[6];
  float* out = (float*)d_out;

  char* ws = (char*)d_ws;
  Tables* T    = (Tables*)ws;                         // ~2 KB
  float*  ss   = (float*)(ws + 8*1024);               // 32 floats
  double* part = (double*)(ws + 16*1024);             // 512*44*8 = 180 KB
  float*  u3   = (float*)(ws + (size_t)1*1024*1024);  // linear, 16 MB

  precompute_kernel<<<1, 1024, 0, stream>>>(g0, mdil, mero, T);
  fused_kernel<<<B*CIN*64, 512, 0, stream>>>(x, u3, T);
  gram_kernel<<<NB_RED, 256, 0, stream>>>(u3, part);
  stats_kernel<<<1, 64, 0, stream>>>(part, weight, gamma, beta, ss);
  final_kernel<<<NPOS/4/256, 256, 0, stream>>>(u3, weight, ss, out);
}

// Round 5
// 116.750 us; speedup vs baseline: 1.9985x; 1.0234x over previous
//
#include <hip/hip_runtime.h>
#include <math.h>
#include <utility>

#define B 4
#define CIN 8
#define COUT 16
#define OR_ 8
#define H_ 128
#define W_ 128
#define HW 16384
#define PLANE HW
#define CH_STR (OR_*HW)        // 131072
#define BATCH_STR (CIN*CH_STR) // 1048576
#define NELEM (B*BATCH_STR)    // 4194304
#define NPOS (B*OR_*HW)        // 524288
#define NB_RED 256

// fused tiling; ODD LDS strides to kill bank conflicts
#define TILE 16
#define CB_DIM 24              // conv buffer rows/cols (tile + 2*4 halo)
#define CB_S   29              // conv buffer row stride (odd -> conflict-free)
#define CB_PL  (CB_DIM*CB_S)   // 696
#define DB_DIM 20              // dilate buffer rows/cols (tile + 2*2 halo)
#define DB_S   21              // odd stride
#define DB_PL  (DB_DIM*DB_S)   // 420

typedef __attribute__((ext_vector_type(4))) float f4;

struct Tables {
  float kdil[CIN][27];
  float kero[CIN][27];
  int   o1[CIN][OR_], o2[CIN][OR_];
  int   iy0[CIN][OR_], ix0[CIN][OR_];
  float w00[CIN][OR_], w01[CIN][OR_], w10[CIN][OR_], w11[CIN][OR_];
  float cf[CIN];
  int   iymin[CIN], iymax[CIN], ixmin[CIN], ixmax[CIN];
};

// ---------------- compile-time tap geometry ----------------
__host__ __device__ constexpr double m_cos(int o) {
  const double r = 0.70710678118654752440;
  const double t[8] = {1.0, r, 0.0, -r, -1.0, -r, 0.0, r};
  return t[o];
}
__host__ __device__ constexpr double m_sin(int o) {
  const double r = 0.70710678118654752440;
  const double t[8] = {0.0, r, 1.0, r, 0.0, -r, -1.0, -r};
  return t[o];
}
// j = (qy+1)*3 + (qx+1)
__host__ __device__ constexpr double tap_dx(int o, int j) {
  return m_cos(o)*(j % 3 - 1) - m_sin(o)*(j / 3 - 1);
}
__host__ __device__ constexpr double tap_dy(int o, int j) {
  return m_sin(o)*(j % 3 - 1) + m_cos(o)*(j / 3 - 1);
}
__host__ __device__ constexpr int ifloor(double v) {
  int i = (int)v;
  return ((double)i > v) ? i - 1 : i;
}
__host__ __device__ constexpr int tap_ix(int o, int j) { return ifloor(tap_dx(o, j)); } // [-2,1]
__host__ __device__ constexpr int tap_iy(int o, int j) { return ifloor(tap_dy(o, j)); }
__host__ __device__ constexpr float tap_fx(int o, int j) { return (float)(tap_dx(o, j) - tap_ix(o, j)); }
__host__ __device__ constexpr float tap_fy(int o, int j) { return (float)(tap_dy(o, j) - tap_iy(o, j)); }
__host__ __device__ constexpr float corner_w(int o, int j, int dyb, int dxb) {
  float fy = tap_fy(o, j), fx = tap_fx(o, j);
  return (dyb ? fy : 1.0f - fy) * (dxb ? fx : 1.0f - fx);
}
__host__ __device__ constexpr int corner_r(int o, int j, int dyb) { return tap_iy(o, j) + dyb + 2; } // 0..4
__host__ __device__ constexpr int corner_c(int o, int j, int i, int dxb) { return i + tap_ix(o, j) + dxb + 2; } // 0..7
__host__ __device__ constexpr bool row_used(int o, int r) {
  for (int j = 0; j < 9; ++j)
    for (int dyb = 0; dyb < 2; ++dyb)
      for (int dxb = 0; dxb < 2; ++dxb)
        if (corner_w(o, j, dyb, dxb) != 0.0f && corner_r(o, j, dyb) == r)
          return true;
  return false;
}

template<int N> struct Rep {
  template<class F> __device__ __forceinline__ static void run(F&& f) {
    Rep<N-1>::run(f);
    f(std::integral_constant<int, N-1>{});
  }
};
template<> struct Rep<0> {
  template<class F> __device__ __forceinline__ static void run(F&&) {}
};

// ---------------- kernels ----------------

__global__ void precompute_kernel(const float* __restrict__ g0,
                                  const float* __restrict__ mdil,
                                  const float* __restrict__ mero,
                                  Tables* __restrict__ T) {
  const int t = threadIdx.x;
  const double TWO_PI = 6.283185307179586476925286766559;
  const double P  = 2.0*0.65/(2.0*0.65 - 1.0);
  const double NU = (2.0*0.65 - 1.0)*pow(2.0*0.65, -P);
  if (t < 432) {
    int which = t / 216;           // 0 = dilate, 1 = erode
    int r = t % 216;
    int c = r / 27;
    int j = r % 27;                // j = (qt+1)*9 + (qy+1)*3 + (qx+1)
    int qt = j/9 - 1;
    int qy = (j/3)%3 - 1;
    int qx = j%3 - 1;
    double dth = qt * (TWO_PI/OR_);
    double c1, c2, c3;
    if (qt == 0) { c1 = qx; c2 = qy; c3 = 0.0; }
    else {
      double h = 0.5*dth;
      double cot = cos(h)/sin(h);
      c1 = h*(qx*cot + qy);
      c2 = h*(-qx + qy*cot);
      c3 = dth;
    }
    const float* m = which ? mero : mdil;
    double a0 = (double)m[c*3+0]*c1;
    double a1 = (double)m[c*3+1]*c2;
    double a2 = (double)m[c*3+2]*c3;
    double s = a0*a0 + a1*a1 + a2*a2;
    float k = (float)(NU * pow(s, P*0.5));
    if (which) T->kero[c][j] = k; else T->kdil[c][j] = k;
  } else if (t >= 512 && t < 512 + CIN*OR_) {
    int r = t - 512;
    int c = r >> 3;
    int o = r & 7;
    float x0 = g0[c*3+0], y0 = g0[c*3+1], th0 = g0[c*3+2];
    float a = (float)(o*(TWO_PI/OR_)) - th0;
    float ca = cosf(a), sa = sinf(a);
    float dxv = -(ca*x0 - sa*y0);
    float dyv = -(sa*x0 + ca*y0);
    float fy0 = floorf(dyv), fx0 = floorf(dxv);
    float fy = dyv - fy0, fx = dxv - fx0;
    T->iy0[c][o] = (int)fy0;
    T->ix0[c][o] = (int)fx0;
    T->w00[c][o] = (1.f-fy)*(1.f-fx);
    T->w01[c][o] = (1.f-fy)*fx;
    T->w10[c][o] = fy*(1.f-fx);
    T->w11[c][o] = fy*fx;
    float tt = th0 * (float)(OR_/TWO_PI);
    float fi = floorf(tt);
    int ci = (int)fi;
    T->o1[c][o] = (o - ci) & 7;
    T->o2[c][o] = (o - ci - 1) & 7;
    if (o == 0) T->cf[c] = tt - fi;
  }
  __syncthreads();
  if (t < CIN) {
    int iymn = 999, iymx = -999, ixmn = 999, ixmx = -999;
    for (int o = 0; o < OR_; ++o) {
      iymn = min(iymn, T->iy0[t][o]); iymx = max(iymx, T->iy0[t][o]);
      ixmn = min(ixmn, T->ix0[t][o]); ixmx = max(ixmx, T->ix0[t][o]);
    }
    T->iymin[t] = iymn; T->iymax[t] = iymx;
    T->ixmin[t] = ixmn; T->ixmax[t] = ixmx;
  }
}

// morph window evaluation from an LDS source (scalar reads, odd strides ->
// conflict-free; compiler merges pairs into ds_read2_b32).
template<int O, int DIL, int PLSTR, int RSTR>
__device__ __forceinline__ void morph_tile_lds(const float* __restrict__ src,
                                               const float* __restrict__ kt,
                                               int row, int gc, float acc[4]) {
  Rep<3>::run([&](auto qc) {
    constexpr int qti = decltype(qc)::value;
    const float* p = src + ((O + qti + 7) & 7) * PLSTR + row * RSTR + gc;
    float win[5][8];
    Rep<5>::run([&](auto rc) {
      constexpr int r = decltype(rc)::value;
      if constexpr (row_used(O, r)) {
        #pragma unroll
        for (int k = 0; k < 8; ++k) win[r][k] = p[r*RSTR + k];
      }
    });
    Rep<9>::run([&](auto jc) {
      constexpr int j = decltype(jc)::value;
      float k = kt[qti*9 + j];
      float base = DIL ? -k : k;
      Rep<4>::run([&](auto ic) {
        constexpr int i = decltype(ic)::value;
        float v = base;
        Rep<4>::run([&](auto cc2) {
          constexpr int cn  = decltype(cc2)::value;
          constexpr int dyb = cn >> 1, dxb = cn & 1;
          constexpr float Wgt = corner_w(O, j, dyb, dxb);
          if constexpr (Wgt != 0.0f) {
            constexpr int R = corner_r(O, j, dyb);
            constexpr int C = corner_c(O, j, i, dxb);
            v = fmaf(Wgt, win[R][C], v);
          }
        });
        acc[i] = DIL ? fmaxf(acc[i], v) : fminf(acc[i], v);
      });
    });
  });
}

template<int O>
__device__ __forceinline__ void dil_wave(const float* __restrict__ cb, float* __restrict__ db,
                                         const float* __restrict__ kt, int lane) {
  #pragma unroll
  for (int it = 0; it < 2; ++it) {
    int g = lane + it*64;
    if (g < 100) {
      int row = g / 5;
      int gc = (g - row*5) * 4;
      float acc[4] = {-INFINITY, -INFINITY, -INFINITY, -INFINITY};
      morph_tile_lds<O, 1, CB_PL, CB_S>(cb, kt, row, gc, acc);
      float* d = db + O*DB_PL + row*DB_S + gc;
      #pragma unroll
      for (int i = 0; i < 4; ++i) d[i] = acc[i];
    }
  }
}

template<int O>
__device__ __forceinline__ void ero_wave(const float* __restrict__ db, float* __restrict__ dst,
                                         const float* __restrict__ kt, int lane) {
  int row = lane >> 2;
  int gc = (lane & 3) * 4;
  float acc[4] = {INFINITY, INFINITY, INFINITY, INFINITY};
  morph_tile_lds<O, 0, DB_PL, DB_S>(db, kt, row, gc, acc);
  f4 v = {acc[0], acc[1], acc[2], acc[3]};
  *(f4*)(dst + O*PLANE + row*W_ + gc) = v;
}

// conv -> dilate -> erode, one (b,c,16x16 tile) per block, 512 threads (8 waves).
// Wave wid owns orientation o = wid everywhere -> all per-(c,o) params scalar.
__global__ __launch_bounds__(512, 4)
void fused_kernel(const float* __restrict__ x, float* __restrict__ u3,
                  const Tables* __restrict__ T) {
  __shared__ float convbuf[8*CB_PL];   // 22.3 KB
  __shared__ float dilbuf[8*DB_PL];    // 13.4 KB
  int blk = blockIdx.x;
  int tx = blk & 7, ty = (blk >> 3) & 7, c = (blk >> 6) & 7, b = blk >> 9;
  int h0 = ty*TILE, w0 = tx*TILE;
  int t = threadIdx.x;
  int wid = t >> 6, lane = t & 63;
  const float* xc = x + b*BATCH_STR + c*CH_STR;

  // ---- stage 1: convection into convbuf ----
  {
    const int o = wid;
    const int iy0 = T->iy0[c][o], ix0 = T->ix0[c][o];
    const float w00 = T->w00[c][o], w01 = T->w01[c][o];
    const float w10 = T->w10[c][o], w11 = T->w11[c][o];
    const float cfv = T->cf[c];
    const float* p1 = xc + T->o1[c][o]*PLANE;
    const float* p2 = xc + T->o2[c][o]*PLANE;
    bool interior = (h0 - 4 + T->iymin[c] >= 0) & (h0 + 20 + T->iymax[c] <= 127)
                  & (w0 - 4 + T->ixmin[c] >= 0) & (w0 + 20 + T->ixmax[c] <= 127)
                  & (h0 >= 16) & (h0 <= 96) & (w0 >= 16) & (w0 <= 96);
    if (interior) {
      // clamp-free: 144 quads (24 rows x 6 col-quads) per wave
      #pragma unroll
      for (int it = 0; it < 3; ++it) {
        int q = lane + it*64;
        if (q < 144) {
          int r = q / 6;
          int cq = q - r*6;
          int iy = h0 - 4 + r + iy0;
          int ix = w0 - 4 + cq*4 + ix0;
          const float* q1 = p1 + iy*W_ + ix;
          const float* q2 = p2 + iy*W_ + ix;
          float a[5], bb[5], cc[5], dd[5];
          #pragma unroll
          for (int k = 0; k < 5; ++k) {
            a[k] = q1[k]; bb[k] = q1[W_+k]; cc[k] = q2[k]; dd[k] = q2[W_+k];
          }
          float* dst = &convbuf[o*CB_PL + r*CB_S + cq*4];
          #pragma unroll
          for (int i = 0; i < 4; ++i) {
            float v1 = w00*a[i] + w01*a[i+1] + w10*bb[i] + w11*bb[i+1];
            float v2 = w00*cc[i] + w01*cc[i+1] + w10*dd[i] + w11*dd[i+1];
            dst[i] = (1.0f - cfv)*v1 + cfv*v2;
          }
        }
      }
    } else {
      // border: clamped scalar path, 576 cells per wave
      #pragma unroll
      for (int it = 0; it < 9; ++it) {
        int cell = lane + it*64;     // < 576
        int r = cell / 24;
        int col = cell - r*24;
        int gh = min(max(h0 - 4 + r, 0), 127);
        int gw = min(max(w0 - 4 + col, 0), 127);
        int iy = gh + iy0, ix = gw + ix0;
        int r0 = min(max(iy, 0), 127), r1 = min(max(iy+1, 0), 127);
        int c0 = min(max(ix, 0), 127), c1 = min(max(ix+1, 0), 127);
        float v1 = w00*p1[r0*W_+c0] + w01*p1[r0*W_+c1] + w10*p1[r1*W_+c0] + w11*p1[r1*W_+c1];
        float v2 = w00*p2[r0*W_+c0] + w01*p2[r0*W_+c1] + w10*p2[r1*W_+c0] + w11*p2[r1*W_+c1];
        convbuf[o*CB_PL + r*CB_S + col] = (1.0f - cfv)*v1 + cfv*v2;
      }
    }
  }
  __syncthreads();

  // ---- stage 2: dilate into dilbuf (per-wave-uniform orientation) ----
  {
    const float* kt = T->kdil[c];
    switch (wid) {
      case 0: dil_wave<0>(convbuf, dilbuf, kt, lane); break;
      case 1: dil_wave<1>(convbuf, dilbuf, kt, lane); break;
      case 2: dil_wave<2>(convbuf, dilbuf, kt, lane); break;
      case 3: dil_wave<3>(convbuf, dilbuf, kt, lane); break;
      case 4: dil_wave<4>(convbuf, dilbuf, kt, lane); break;
      case 5: dil_wave<5>(convbuf, dilbuf, kt, lane); break;
      case 6: dil_wave<6>(convbuf, dilbuf, kt, lane); break;
      default: dil_wave<7>(convbuf, dilbuf, kt, lane); break;
    }
  }
  __syncthreads();

  // ---- stage 2b: replicate dilbuf halo for edge tiles (clamped semantics) ----
  if ((h0 == 0) | (h0 == 112) | (w0 == 0) | (w0 == 112)) {
    #pragma unroll
    for (int k = 0; k < 7; ++k) {
      int cc = t + k*512;                // over 3200 = 8*20*20
      if (cc < 3200) {
        int col = cc % DB_DIM;
        int tmp = cc / DB_DIM;
        int row = tmp % DB_DIM;
        int o = tmp / DB_DIM;
        int vh = h0 - 2 + row, vw = w0 - 2 + col;
        int dr = min(max(vh, 0), 127) - vh;
        int dc = min(max(vw, 0), 127) - vw;
        if ((dr != 0) | (dc != 0)) {
          dilbuf[o*DB_PL + (row + dr)*DB_S + col + dc] ==
          dilbuf[o*DB_PL + row*DB_S + col];   // placeholder, replaced below
        }
      }
    }
  }
  // NOTE: the line above is rewritten correctly in the real pass below.
  __syncthreads();
  if ((h0 == 0) | (h0 == 112) | (w0 == 0) | (w0 == 112)) {
    #pragma unroll
    for (int k = 0; k < 7; ++k) {
      int cc = t + k*512;
      if (cc < 3200) {
        int col = cc % DB_DIM;
        int tmp = cc / DB_DIM;
        int row = tmp % DB_DIM;
        int o = tmp / DB_DIM;
        int vh = h0 - 2 + row, vw = w0 - 2 + col;
        int dr = min(max(vh, 0), 127) - vh;
        int dc = min(max(vw, 0), 127) - vw;
        if ((dr != 0) | (dc != 0)) {
          dilbuf[o*DB_PL + row*DB_S + col] =
            dilbuf[o*DB_PL + (row + dr)*DB_S + col + dc];
        }
      }
    }
  }
  __syncthreads();

  // ---- stage 3: erode -> u3 (linear) ----
  {
    const float* kt = T->kero[c];
    float* dst = u3 + (b*CIN + c)*(OR_*PLANE) + h0*W_ + w0;
    switch (wid) {
      case 0: ero_wave<0>(dilbuf, dst, kt, lane); break;
      case 1: ero_wave<1>(dilbuf, dst, kt, lane); break;
      case 2: ero_wave<2>(dilbuf, dst, kt, lane); break;
      case 3: ero_wave<3>(dilbuf, dst, kt, lane); break;
      case 4: ero_wave<4>(dilbuf, dst, kt, lane); break;
      case 5: ero_wave<5>(dilbuf, dst, kt, lane); break;
      case 6: ero_wave<6>(dilbuf, dst, kt, lane); break;
      default: ero_wave<7>(dilbuf, dst, kt, lane); break;
    }
  }
}

__global__ void gram_kernel(const float* __restrict__ u, double* __restrict__ part) {
  int t8 = blockIdx.x*256 + threadIdx.x;     // NPOS/8 = 65536 threads
  int hw = (t8 & 2047) << 3;
  int o  = (t8 >> 11) & 7;
  int b  = t8 >> 14;
  const float* base = u + b*BATCH_STR + o*PLANE + hw;
  f4 v0[8], v1[8];
  #pragma unroll
  for (int c = 0; c < 8; c++) {
    v0[c] = *(const f4*)(base + c*CH_STR);
    v1[c] = *(const f4*)(base + c*CH_STR + 4);
  }
  float S[8], G[36];
  #pragma unroll
  for (int c = 0; c < 8; c++)
    S[c] = (v0[c].x + v0[c].y) + (v0[c].z + v0[c].w)
         + (v1[c].x + v1[c].y) + (v1[c].z + v1[c].w);
  {
    int t = 0;
    #pragma unroll
    for (int c = 0; c < 8; c++)
      #pragma unroll
      for (int c2 = c; c2 < 8; c2++) {
        G[t] = v0[c].x*v0[c2].x + v0[c].y*v0[c2].y + v0[c].z*v0[c2].z + v0[c].w*v0[c2].w
             + v1[c].x*v1[c2].x + v1[c].y*v1[c2].y + v1[c].z*v1[c2].z + v1[c].w*v1[c2].w;
        t++;
      }
  }
  __shared__ double lds[4][44];
  int lane = threadIdx.x & 63;
  int wave = threadIdx.x >> 6;
  for (int t = 0; t < 44; t++) {
    double vv = (double)((t < 8) ? S[t] : G[t-8]);
    for (int off = 32; off; off >>= 1) vv += __shfl_down(vv, off);
    if (lane == 0) lds[wave][t] = vv;
  }
  __syncthreads();
  if (threadIdx.x < 44) {
    part[blockIdx.x*44 + threadIdx.x] =
      lds[0][threadIdx.x] + lds[1][threadIdx.x] + lds[2][threadIdx.x] + lds[3][threadIdx.x];
  }
}

__global__ void stats_kernel(const double* __restrict__ part, const float* __restrict__ weight,
                             const float* __restrict__ gamma, const float* __restrict__ beta,
                             float* __restrict__ ss) {
  __shared__ double tot[44];
  int t = threadIdx.x;
  if (t < 352) {
    int cnt = t >> 3, j = t & 7;
    double s = 0.0;
    #pragma unroll 8
    for (int k = 0; k < 32; ++k) s += part[(j + (k << 3))*44 + cnt];
    s += __shfl_down(s, 4);
    s += __shfl_down(s, 2);
    s += __shfl_down(s, 1);
    if (j == 0) tot[cnt] = s;
  }
  __syncthreads();
  if (t < 16) {
    double m = 0.0;
    for (int c = 0; c < 8; c++) m += (double)weight[c*COUT + t] * tot[c];
    double e2 = 0.0;
    int idx = 8;
    for (int c = 0; c < 8; c++)
      for (int c2 = c; c2 < 8; c2++) {
        double wp = (double)weight[c*COUT + t] * (double)weight[c2*COUT + t];
        e2 += (c2 == c ? 1.0 : 2.0) * wp * tot[idx];
        idx++;
      }
    double N = (double)NPOS;
    m /= N; e2 /= N;
    double var = e2 - m*m;
    double inv = rsqrt(var + 1e-5);
    float sc = (float)(inv * (double)gamma[t]);
    ss[t]      = sc;
    ss[16 + t] = beta[t] - (float)m * sc;
  }
}

__global__ void final_kernel(const float* __restrict__ u, const float* __restrict__ weight,
                             const float* __restrict__ ss, float* __restrict__ out) {
  __shared__ float Wsh[8][16];
  __shared__ float scale[16], shift[16];
  int t = threadIdx.x;
  if (t < 128) Wsh[t >> 4][t & 15] = weight[t];
  if (t < 16) { scale[t] = ss[t]; shift[t] = ss[16 + t]; }
  __syncthreads();
  int t4 = blockIdx.x*256 + threadIdx.x;     // 131072 threads
  int hw = (t4 & 4095) << 2;
  int o  = (t4 >> 12) & 7;
  int b  = t4 >> 15;
  const float* base = u + b*BATCH_STR + o*PLANE + hw;
  f4 v[8];
  #pragma unroll
  for (int c = 0; c < 8; c++) v[c] = *(const f4*)(base + c*CH_STR);
  float* ob = out + b*(COUT*CH_STR) + o*PLANE + hw;
  #pragma unroll
  for (int d = 0; d < 16; d++) {
    f4 y = {0.f, 0.f, 0.f, 0.f};
    #pragma unroll
    for (int c = 0; c < 8; c++) {
      float wv = Wsh[c][d];
      y.x = fmaf(v[c].x, wv, y.x);
      y.y = fmaf(v[c].y, wv, y.y);
      y.z = fmaf(v[c].z, wv, y.z);
      y.w = fmaf(v[c].w, wv, y.w);
    }
    float sc = scale[d], sh = shift[d];
    f4 r = { fmaf(y.x, sc, sh), fmaf(y.y, sc, sh), fmaf(y.z, sc, sh), fmaf(y.w, sc, sh) };
    *(f4*)(ob + d*CH_STR) = r;
  }
}

extern "C" void kernel_launch(void* const* d_in, const int* in_sizes, int n_in,
                              void* d_out, int out_size, void* d_ws, size_t ws_size,
                              hipStream_t stream) {
  const float* x      = (const float*)d_in[0];
  const float* g0     = (const float*)d_in[1];
  const float* mdil   = (const float*)d_in[2];
  const float* mero   = (const float*)d_in[3];
  const float* weight = (const float*)d_in[4];
  const float* gamma  = (const float*)d_in[5];
  const float* beta   = (const float*)d_in[6];
  float* out = (float*)d_out;

  char* ws = (char*)d_ws;
  Tables* T    = (Tables*)ws;                         // ~3 KB
  float*  ss   = (float*)(ws + 8*1024);               // 32 floats
  double* part = (double*)(ws + 16*1024);             // 256*44*8 = 90 KB
  float*  u3   = (float*)(ws + (size_t)1*1024*1024);  // linear, 16 MB

  precompute_kernel<<<1, 1024, 0, stream>>>(g0, mdil, mero, T);
  fused_kernel<<<B*CIN*64, 512, 0, stream>>>(x, u3, T);
  gram_kernel<<<NB_RED, 256, 0, stream>>>(u3, part);
  stats_kernel<<<1, 384, 0, stream>>>(part, weight, gamma, beta, ss);
  final_kernel<<<NPOS/4/256, 256, 0, stream>>>(u3, weight, ss, out);
}